// Round 3
// baseline (447.293 us; speedup 1.0000x reference)
//
#include <hip/hip_runtime.h>
#include <hip/hip_bf16.h>
#include <stdint.h>

typedef __attribute__((ext_vector_type(8))) short short8;   // 8 bf16 (4 VGPRs)
typedef __attribute__((ext_vector_type(4))) float f32x4;

#define IN_DIM 128
#define OUT_DIM 128
#define NROWS 524288
#define TILES_PER_BLOCK 4
#define NBLOCKS (NROWS / (64 * TILES_PER_BLOCK))   // 2048

__device__ __forceinline__ ushort f2bf(float f) {
    __hip_bfloat16 h = __float2bfloat16(f);
    union { __hip_bfloat16 h; ushort u; } cv;
    cv.h = h;
    return cv.u;
}

// y[m][n] = sum_k x[m][k] * W[n][k] + b[n]
// A = x (row=l&15, k=(l>>4)*8+j contiguous), B = W^T (col=l&15 -> W row, k contiguous)
__global__ __launch_bounds__(256) void linear_kernel(
    const float* __restrict__ x,
    const float* __restrict__ wgt,
    const float* __restrict__ bias,
    float* __restrict__ out)
{
    // W in MFMA B-fragment order: entry g=(kk*8+nt)*64+lane holds 8 bf16 (16B)
    __shared__ short8 wlds[2048];   // 32 KiB

    const int t = threadIdx.x;

    // ---- stage W f32 -> bf16 fragments in LDS (W is L2-resident: 64 KB) ----
    #pragma unroll
    for (int i = 0; i < 8; ++i) {
        int g  = i * 256 + t;
        int kk = g >> 9, nt = (g >> 6) & 7, ln = g & 63;
        int row   = nt * 16 + (ln & 15);
        int kbase = kk * 32 + ((ln >> 4) << 3);
        const float* src = wgt + row * IN_DIM + kbase;
        f32x4 lo = *reinterpret_cast<const f32x4*>(src);
        f32x4 hi = *reinterpret_cast<const f32x4*>(src + 4);
        short8 v;
        v[0] = (short)f2bf(lo[0]); v[1] = (short)f2bf(lo[1]);
        v[2] = (short)f2bf(lo[2]); v[3] = (short)f2bf(lo[3]);
        v[4] = (short)f2bf(hi[0]); v[5] = (short)f2bf(hi[1]);
        v[6] = (short)f2bf(hi[2]); v[7] = (short)f2bf(hi[3]);
        wlds[g] = v;
    }

    const int l  = t & 63;
    const int wv = t >> 6;      // wave id 0..3
    const int r  = l & 15;      // fragment row/col within 16
    const int q  = l >> 4;      // quarter

    // bias fragment: col = nt*16 + r
    float bfrag[8];
    #pragma unroll
    for (int nt = 0; nt < 8; ++nt) bfrag[nt] = bias[nt * 16 + r];

    __syncthreads();

    const long tile0 = (long)blockIdx.x * TILES_PER_BLOCK;
    for (int tt = 0; tt < TILES_PER_BLOCK; ++tt) {
        const long m0 = (tile0 + tt) * 64 + wv * 16;   // this wave's 16-row strip
        const float* xp = x + (m0 + r) * IN_DIM + (q << 3);

        // A fragments: 8 contiguous f32 per lane per K-step -> bf16x8
        short8 a[4];
        #pragma unroll
        for (int kk = 0; kk < 4; ++kk) {
            f32x4 lo = *reinterpret_cast<const f32x4*>(xp + kk * 32);
            f32x4 hi = *reinterpret_cast<const f32x4*>(xp + kk * 32 + 4);
            short8 v;
            v[0] = (short)f2bf(lo[0]); v[1] = (short)f2bf(lo[1]);
            v[2] = (short)f2bf(lo[2]); v[3] = (short)f2bf(lo[3]);
            v[4] = (short)f2bf(hi[0]); v[5] = (short)f2bf(hi[1]);
            v[6] = (short)f2bf(hi[2]); v[7] = (short)f2bf(hi[3]);
            a[kk] = v;
        }

        f32x4 acc[8];
        #pragma unroll
        for (int nt = 0; nt < 8; ++nt) acc[nt] = (f32x4)(0.0f);

        #pragma unroll
        for (int kk = 0; kk < 4; ++kk) {
            #pragma unroll
            for (int nt = 0; nt < 8; ++nt) {
                acc[nt] = __builtin_amdgcn_mfma_f32_16x16x32_bf16(
                    a[kk], wlds[(kk * 8 + nt) * 64 + l], acc[nt], 0, 0, 0);
            }
        }

        // C/D: col = l&15 (+nt*16), row = q*4 + j
        float* op = out + (m0 + (q << 2)) * OUT_DIM + r;
        #pragma unroll
        for (int nt = 0; nt < 8; ++nt) {
            #pragma unroll
            for (int j = 0; j < 4; ++j) {
                op[j * OUT_DIM + nt * 16] = acc[nt][j] + bfrag[nt];
            }
        }
    }
}

extern "C" void kernel_launch(void* const* d_in, const int* in_sizes, int n_in,
                              void* d_out, int out_size, void* d_ws, size_t ws_size,
                              hipStream_t stream) {
    const float* x  = (const float*)d_in[0];
    const float* w  = (const float*)d_in[1];
    const float* b  = (const float*)d_in[2];
    float* out      = (float*)d_out;
    linear_kernel<<<dim3(NBLOCKS), dim3(256), 0, stream>>>(x, w, b, out);
}